// Round 15
// baseline (156.704 us; speedup 1.0000x reference)
//
#include <hip/hip_runtime.h>
#include <math.h>

#define HH 1024
#define WW 1024
#define OUTW 58            // output columns per wave (64 lanes - 6 halo)
#define RPB 4              // output rows per WAVE (r13: RPB=2 regressed; 4 is opt)
#define WPB 4              // waves per block (independent y-strips, no barrier)
#define NF10 10            // staged fields: dep, alb x3, nrm x3, inp x3
#define OFF(i) ((i)*8 - (i)*((i)-1)/2)   // packed upper-tri row offset

// Hard-won constraints (rounds 4/7/10/11/12/13/14):
//  - VGPR bucket MUST stay 128 (occ scales with bucket: 34/16/9.7% at
//    64/128/216); regs-for-ILP sells waves (r11). Peak live floats <= ~120.
//  - WRITE_SIZE ~13.5 MB is the no-spill invariant (r7: 40 MB scratch).
//  - Cross-lane ops never inside divergent flow (r8).
//  - global_load_lds: SOURCE is per-lane VGPR address (lane i must pass
//    base+i); DEST is wave-uniform LDS base + lane*4 (r14 bug: missing +L).

// DPP move, bound_ctrl=1 (invalid lanes read 0)
template<int CTRL>
__device__ __forceinline__ float dpp0(float x) {
    return __int_as_float(
        __builtin_amdgcn_update_dpp(0, __float_as_int(x), CTRL, 0xf, 0xf, true));
}
// whole-wave shift right by 1 lane (crosses 16-lane row boundaries)
__device__ __forceinline__ float wshr1(float x) { return dpp0<0x138>(x); }

// fp32 reciprocal: v_rcp_f32 + 1 Newton step (~1ulp); LDL^T is sqrt-free
__device__ __forceinline__ float frcp_fast(float s) {
    float r = __builtin_amdgcn_rcpf(s);
    return r * fmaf(-s, r, 2.0f);
}

typedef const __attribute__((address_space(1))) unsigned int* gptr_t;
typedef __attribute__((address_space(3))) unsigned int* lptr_t;

__global__ __launch_bounds__(WPB * 64, 2) void ls_sep_kernel(
    const float* __restrict__ inp,    // [3,H,W]
    const float* __restrict__ dep,    // [1,H,W]
    const float* __restrict__ alb,    // [3,H,W]
    const float* __restrict__ nrm,    // [3,H,W]
    float* __restrict__ out)          // [3,H,W]
{
    // per-wave private ring: 2 slots x 10 fields x 64 lanes (20 KB/block)
    __shared__ float ring[WPB][2][NF10][64];

    const int L  = threadIdx.x & 63;          // lane 0..63
    const int wv = threadIdx.x >> 6;          // wave 0..3 (independent y-strip)
    const int HW = HH * WW;
    const int x0 = OUTW * blockIdx.x - 3;     // wave-uniform first column
    const int x  = x0 + L;                    // lane's column (may be OOB)
    const int y0 = (RPB * WPB) * blockIdx.y + RPB * wv;
    const int px = x - 3;                     // output pixel column for this lane

    const int xc    = min(max(x, 0), WW - 1);
    const float xok = (x >= 0 && x < WW) ? 1.f : 0.f;
    // edge blocks: lane span crosses image/allocation bounds -> fallback path
    const bool edgeBlk = (blockIdx.x == 0) || (blockIdx.x == gridDim.x - 1);

    float C[60];                              // running column sums (7 rows in y)
    #pragma unroll
    for (int k = 0; k < 60; k++) C[k] = 0.f;

    // accumulate 10 staged values into C with signed validity s
    auto acc_vals = [&](const float fv7[7], const float yv[3], float s) {
        float f8[8];
        f8[0] = 1.f;
        #pragma unroll
        for (int i = 0; i < 7; i++) f8[i + 1] = fv7[i];
        float fs[8];
        #pragma unroll
        for (int i = 0; i < 8; i++) fs[i] = f8[i] * s;
        int k = 0;
        #pragma unroll
        for (int i = 0; i < 8; i++)
            #pragma unroll
            for (int j = i; j < 8; j++) { C[k] = fmaf(fs[i], f8[j], C[k]); k++; }
        #pragma unroll
        for (int i = 0; i < 8; i++)
            #pragma unroll
            for (int c = 0; c < 3; c++)
                C[36 + i * 3 + c] = fmaf(fs[i], yv[c], C[36 + i * 3 + c]);
    };

    // direct global accumulate (preload + leaving rows; L1/L2-warm for leave)
    auto acc_row_g = [&](int yy, float sgn) {
        const int yc = min(max(yy, 0), HH - 1);
        const float ok = (yy >= 0 && yy < HH) ? xok : 0.f;
        const int p = yc * WW + xc;
        float fv7[7], yv[3];
        fv7[0] = dep[p];
        fv7[1] = alb[p]; fv7[2] = alb[p + HW]; fv7[3] = alb[p + 2 * HW];
        fv7[4] = nrm[p]; fv7[5] = nrm[p + HW]; fv7[6] = nrm[p + 2 * HW];
        yv[0] = inp[p]; yv[1] = inp[p + HW]; yv[2] = inp[p + 2 * HW];
        acc_vals(fv7, yv, sgn * ok);
    };

    // async prefetch of row yy into ring slot.
    // interior: global_load_lds — per-lane SOURCE addr (base + L), wave-uniform
    // LDS dest base (HW scatters to base + lane*4). edge: per-lane clamped
    // load + ds_write fallback (x-clamp not expressible in the DMA form).
    auto prefetch_row = [&](int yy, int slot) {
        const int yc = min(max(yy, 0), HH - 1);
        if (!edgeBlk) {
            const float* bp[NF10] = {
                dep + yc * WW + x0,
                alb + yc * WW + x0, alb + HW + yc * WW + x0, alb + 2 * HW + yc * WW + x0,
                nrm + yc * WW + x0, nrm + HW + yc * WW + x0, nrm + 2 * HW + yc * WW + x0,
                inp + yc * WW + x0, inp + HW + yc * WW + x0, inp + 2 * HW + yc * WW + x0};
            #pragma unroll
            for (int f = 0; f < NF10; f++)
                __builtin_amdgcn_global_load_lds(
                    (gptr_t)(bp[f] + L), (lptr_t)&ring[wv][slot][f][0], 4, 0, 0);
        } else {
            const int p = yc * WW + xc;       // per-lane clamped (safe)
            ring[wv][slot][0][L] = dep[p];
            ring[wv][slot][1][L] = alb[p];
            ring[wv][slot][2][L] = alb[p + HW];
            ring[wv][slot][3][L] = alb[p + 2 * HW];
            ring[wv][slot][4][L] = nrm[p];
            ring[wv][slot][5][L] = nrm[p + HW];
            ring[wv][slot][6][L] = nrm[p + 2 * HW];
            ring[wv][slot][7][L] = inp[p];
            ring[wv][slot][8][L] = inp[p + HW];
            ring[wv][slot][9][L] = inp[p + 2 * HW];
        }
    };

    // accumulate entering row from ring slot
    auto acc_enter_lds = [&](int yy, int slot) {
        const float ok = (yy >= 0 && yy < HH) ? xok : 0.f;
        float fv7[7], yv[3];
        #pragma unroll
        for (int i = 0; i < 7; i++) fv7[i] = ring[wv][slot][i][L];
        #pragma unroll
        for (int c = 0; c < 3; c++) yv[c] = ring[wv][slot][7 + c][L];
        acc_vals(fv7, yv, ok);
    };

    // preload rows y0-4 .. y0+2 direct (loop body does enter(y+3), leave(y-4))
    #pragma unroll 1
    for (int yy = y0 - 4; yy < y0 + 3; yy++) acc_row_g(yy, 1.f);
    // prime the ring with the first entering row
    prefetch_row(y0 + 3, (y0 + 3) & 1);

    const int idxm4 = ((L - 4) & 63) << 2;    // bpermute byte index for lane L-4
    const int pxc = min(max(px, 0), WW - 1);
    const bool do_store = (L >= 6) && (px < WW);

    // Batched horizontal 7-tap over lanes L-6..L for 12 values at once.
    // MUST be called by all 64 lanes (cross-lane inside).
    auto htap12 = [&](int base, float* dst) {
        float t2a[12];
        int pma[12];
        #pragma unroll
        for (int j = 0; j < 12; j++) {
            const float xv = C[base + j];
            const float w1 = wshr1(xv);       // C(L-1)
            const float t1 = xv + w1;         // L-1..L
            const float w2 = wshr1(w1);       // C(L-2)
            const float t3 = t1 + w2;         // L-2..L
            const float w3 = wshr1(w2);       // C(L-3)
            t2a[j] = t3 + w3;                 // L-3..L
            pma[j] = __builtin_amdgcn_ds_bpermute(idxm4, __float_as_int(t3));
        }
        #pragma unroll
        for (int j = 0; j < 12; j++)
            dst[j] = t2a[j] + __int_as_float(pma[j]);   // + (L-6..L-4)
    };

    #pragma unroll 1
    for (int y = y0; y < y0 + RPB; y++) {
        // wait for last iteration's prefetch (issued ~2500 cyc ago -> ~free);
        // the asm clobber stops LLVM hoisting the ring ds_reads above it
        __builtin_amdgcn_s_waitcnt(0x0f70);   // vmcnt(0), lgkm/exp unconstrained
        asm volatile("" ::: "memory");
        // issue next prefetch immediately: maximum lead time
        prefetch_row(y + 4, (y + 4) & 1);

        // entering row y+3 from the ring (ds_read, ~6 cyc throughput)
        acc_enter_lds(y + 3, (y + 3) & 1);
        // leaving row y-4 direct global (streamed 7 rows ago -> L1/L2-warm)
        acc_row_g(y - 4, -1.f);

        // center-pixel features (global, warm rows)
        const int pc = y * WW + pxc;
        float cf[8];
        cf[0] = 1.f;
        cf[1] = dep[pc];
        cf[2] = alb[pc]; cf[3] = alb[pc + HW]; cf[4] = alb[pc + 2 * HW];
        cf[5] = nrm[pc]; cf[6] = nrm[pc + HW]; cf[7] = nrm[pc + 2 * HW];

        // ---- horizontal taps for AtA (AtY deferred past the solve) ----
        float W[36];
        htap12(0,  &W[0]);
        htap12(12, &W[12]);
        htap12(24, &W[24]);
        #pragma unroll
        for (int i = 0; i < 8; i++) W[OFF(i)] += 1.0e-4f;

        // ---- fp32 LDL^T (sqrt-free). W row i keeps R_ij = d_i*U_ij ----
        float idv[8];
        #pragma unroll
        for (int i = 0; i < 8; i++) {
            #pragma unroll
            for (int k = 0; k < i; k++) {
                const float c = W[OFF(k) + i - k] * idv[k];   // U_ki
                #pragma unroll
                for (int j = i; j < 8; j++)
                    W[OFF(i) + j - i] = fmaf(-c, W[OFF(k) + j - k], W[OFF(i) + j - i]);
            }
            idv[i] = frcp_fast(W[OFF(i)]);    // 1/d_i
        }

        // forward: vt_i = idv_i * (cf_i - sum_{k<i} R_ki * vt_k)
        float vt[8];
        #pragma unroll
        for (int i = 0; i < 8; i++) {
            float s = cf[i];
            #pragma unroll
            for (int k = 0; k < i; k++)
                s = fmaf(-W[OFF(k) + i - k], vt[k], s);
            vt[i] = s * idv[i];
        }
        // back: w_i = vt_i - idv_i * sum_{j>i} R_ij * w_j
        float w[8];
        #pragma unroll
        for (int i = 7; i >= 0; i--) {
            float t = 0.f;
            #pragma unroll
            for (int j = i + 1; j < 8; j++)
                t = fmaf(W[OFF(i) + j - i], w[j], t);
            w[i] = fmaf(-idv[i], t, vt[i]);
        }

        // ---- deferred AtY taps (batched) + output dot products:
        //      ALL lanes execute; only the store is predicated ----
        float r[3] = {0.f, 0.f, 0.f};
        {
            float SY[12];
            htap12(36, SY);                   // AtY for i=0..3
            #pragma unroll
            for (int i = 0; i < 4; i++)
                #pragma unroll
                for (int c = 0; c < 3; c++)
                    r[c] = fmaf(w[i], SY[i * 3 + c], r[c]);
            htap12(48, SY);                   // AtY for i=4..7
            #pragma unroll
            for (int i = 0; i < 4; i++)
                #pragma unroll
                for (int c = 0; c < 3; c++)
                    r[c] = fmaf(w[i + 4], SY[i * 3 + c], r[c]);
        }

        if (do_store) {
            const int p = y * WW + px;
            #pragma unroll
            for (int c = 0; c < 3; c++)
                out[c * HW + p] = r[c];
        }
    }
}

extern "C" void kernel_launch(void* const* d_in, const int* in_sizes, int n_in,
                              void* d_out, int out_size, void* d_ws, size_t ws_size,
                              hipStream_t stream) {
    const float* inp = (const float*)d_in[0];
    const float* dep = (const float*)d_in[1];
    const float* alb = (const float*)d_in[2];
    const float* nrm = (const float*)d_in[3];
    float* out = (float*)d_out;
    dim3 grid((WW + OUTW - 1) / OUTW, HH / (RPB * WPB));   // 18 x 64, 256-thr blocks
    ls_sep_kernel<<<grid, dim3(WPB * 64), 0, stream>>>(inp, dep, alb, nrm, out);
}

// Round 16
// 137.014 us; speedup vs baseline: 1.1437x; 1.1437x over previous
//
#include <hip/hip_runtime.h>
#include <math.h>

#define HH 1024
#define WW 1024
#define OUTW 58            // output columns per wave (64 lanes - 6 halo)
#define RPB 4              // output rows per WAVE (r13: RPB=2 regressed; 4 is opt)
#define WPB 4              // waves per block (independent y-strips, no barrier)

// Hard-won constraints (rounds 4..15):
//  - VGPR bucket MUST stay 128 (occ scales with bucket); peak live <= ~120
//    floats or the allocator spills at 128 rather than going to 256 (r7).
//    WRITE_SIZE ~13.5 MB is the no-spill invariant.
//  - Cross-lane ops never inside divergent flow (r8).
//  - s_waitcnt vmcnt(0) drains ALL VMEM incl. output stores -> LDS-ring
//    prefetch with per-iter vmcnt(0) serializes the loop (r15: 85 us).
//  - More waves / fewer waves / regs-for-ILP all falsified (r13/r11).
//  - This round: packed fp32 (v_pk_fma_f32) on acc/LDLT/dots: -15% VALU
//    at identical storage and rounding.

typedef float v2f __attribute__((ext_vector_type(2)));

// packed-row AtA layout: row i stores feature-pairs p = i/2 .. 3
// (20 v2f = 40 floats; 4 sub-diagonal slots are consistent duplicates,
//  never read by the solve)
__device__ __constant__ const int RS_[8] = {0, 4, 8, 11, 14, 16, 18, 19};
#define RS(i) ((i) == 0 ? 0 : (i) == 1 ? 4 : (i) == 2 ? 8 : (i) == 3 ? 11 : \
               (i) == 4 ? 14 : (i) == 5 ? 16 : (i) == 6 ? 18 : 19)

// DPP move, bound_ctrl=1 (invalid lanes read 0)
template<int CTRL>
__device__ __forceinline__ float dpp0(float x) {
    return __int_as_float(
        __builtin_amdgcn_update_dpp(0, __float_as_int(x), CTRL, 0xf, 0xf, true));
}
// whole-wave shift right by 1 lane (crosses 16-lane row boundaries)
__device__ __forceinline__ float wshr1(float x) { return dpp0<0x138>(x); }

// fp32 reciprocal: v_rcp_f32 + 1 Newton step (~1ulp); LDL^T is sqrt-free
__device__ __forceinline__ float frcp_fast(float s) {
    float r = __builtin_amdgcn_rcpf(s);
    return r * fmaf(-s, r, 2.0f);
}

// batched horizontal 7-tap over lanes L-6..L for N v2f values (2N scalars).
// MUST be called by all 64 lanes (cross-lane DPP + bpermute inside).
template<int N>
__device__ __forceinline__ void htapv(const v2f* src, v2f* dst, int idxm4) {
    float t2a[2 * N];
    int pma[2 * N];
    #pragma unroll
    for (int j = 0; j < N; j++) {
        #pragma unroll
        for (int h = 0; h < 2; h++) {
            const float xv = h ? src[j].y : src[j].x;
            const float w1 = wshr1(xv);       // C(L-1)
            const float t1 = xv + w1;         // L-1..L
            const float w2 = wshr1(w1);       // C(L-2)
            const float t3 = t1 + w2;         // L-2..L
            const float w3 = wshr1(w2);       // C(L-3)
            t2a[2 * j + h] = t3 + w3;         // L-3..L
            pma[2 * j + h] = __builtin_amdgcn_ds_bpermute(idxm4, __float_as_int(t3));
        }
    }
    #pragma unroll
    for (int j = 0; j < N; j++) {
        v2f d;
        d.x = t2a[2 * j]     + __int_as_float(pma[2 * j]);
        d.y = t2a[2 * j + 1] + __int_as_float(pma[2 * j + 1]);
        dst[j] = d;
    }
}

__global__ __launch_bounds__(WPB * 64, 2) void ls_sep_kernel(
    const float* __restrict__ inp,    // [3,H,W]
    const float* __restrict__ dep,    // [1,H,W]
    const float* __restrict__ alb,    // [3,H,W]
    const float* __restrict__ nrm,    // [3,H,W]
    float* __restrict__ out)          // [3,H,W]
{
    const int L  = threadIdx.x & 63;          // lane 0..63
    const int wv = threadIdx.x >> 6;          // wave 0..3 (independent y-strip)
    const int HW = HH * WW;
    const int x  = OUTW * blockIdx.x - 3 + L; // lane's column (may be OOB)
    const int y0 = (RPB * WPB) * blockIdx.y + RPB * wv;
    const int px = x - 3;                     // output pixel column for this lane

    const int xc    = min(max(x, 0), WW - 1);
    const float xok = (x >= 0 && x < WW) ? 1.f : 0.f;

    // running column sums: AtA packed rows (20 v2f) + AtY [c][featpair] (12 v2f)
    v2f CCA[20], CY[12];
    #pragma unroll
    for (int k = 0; k < 20; k++) CCA[k] = (v2f){0.f, 0.f};
    #pragma unroll
    for (int k = 0; k < 12; k++) CY[k] = (v2f){0.f, 0.f};

    // packed accumulate of one pixel's products with signed validity s
    auto acc_vals = [&](const float f8[8], const float yv[3], float s) {
        v2f F[4], Fs[4];
        #pragma unroll
        for (int p = 0; p < 4; p++) {
            F[p].x = f8[2 * p]; F[p].y = f8[2 * p + 1];
            Fs[p] = F[p] * (v2f){s, s};                        // v_pk_mul_f32
        }
        #pragma unroll
        for (int i = 0; i < 8; i++) {
            const float fsi = (i & 1) ? Fs[i >> 1].y : Fs[i >> 1].x;
            const v2f fb = (v2f){fsi, fsi};
            #pragma unroll
            for (int p = i >> 1; p < 4; p++)
                CCA[RS(i) + p - (i >> 1)] =
                    __builtin_elementwise_fma(fb, F[p], CCA[RS(i) + p - (i >> 1)]);
        }
        #pragma unroll
        for (int c = 0; c < 3; c++) {
            const v2f yb = (v2f){yv[c], yv[c]};
            #pragma unroll
            for (int p = 0; p < 4; p++)
                CY[c * 4 + p] = __builtin_elementwise_fma(Fs[p], yb, CY[c * 4 + p]);
        }
    };

    auto acc_row_g = [&](int yy, float sgn) {
        const int yc = min(max(yy, 0), HH - 1);
        const float ok = (yy >= 0 && yy < HH) ? xok : 0.f;
        const int p = yc * WW + xc;
        float f8[8], yv[3];
        f8[0] = 1.f;
        f8[1] = dep[p];
        f8[2] = alb[p]; f8[3] = alb[p + HW]; f8[4] = alb[p + 2 * HW];
        f8[5] = nrm[p]; f8[6] = nrm[p + HW]; f8[7] = nrm[p + 2 * HW];
        yv[0] = inp[p]; yv[1] = inp[p + HW]; yv[2] = inp[p + 2 * HW];
        acc_vals(f8, yv, sgn * ok);
    };

    // preload rows y0-4 .. y0+2 (loop body does add(y+3), sub(y-4))
    #pragma unroll 1
    for (int yy = y0 - 4; yy < y0 + 3; yy++) acc_row_g(yy, 1.f);

    const int idxm4 = ((L - 4) & 63) << 2;    // bpermute byte index for lane L-4
    const int pxc = min(max(px, 0), WW - 1);
    const bool do_store = (L >= 6) && (px < WW);

    #pragma unroll 1
    for (int y = y0; y < y0 + RPB; y++) {
        acc_row_g(y + 3, 1.f);
        acc_row_g(y - 4, -1.f);

        // center-pixel features EARLY (load latency hides under taps)
        const int pc = y * WW + pxc;
        float cf[8];
        cf[0] = 1.f;
        cf[1] = dep[pc];
        cf[2] = alb[pc]; cf[3] = alb[pc + HW]; cf[4] = alb[pc + 2 * HW];
        cf[5] = nrm[pc]; cf[6] = nrm[pc + HW]; cf[7] = nrm[pc + 2 * HW];

        // ---- horizontal taps for AtA (AtY deferred past the solve) ----
        v2f WA[20];
        htapv<5>(&CCA[0],  &WA[0],  idxm4);
        htapv<5>(&CCA[5],  &WA[5],  idxm4);
        htapv<5>(&CCA[10], &WA[10], idxm4);
        htapv<5>(&CCA[15], &WA[15], idxm4);
        #pragma unroll
        for (int i = 0; i < 8; i++) {          // +eps on diagonals
            if (i & 1) WA[RS(i)].y += 1.0e-4f;
            else       WA[RS(i)].x += 1.0e-4f;
        }

        // element (i,j), j>=i, from packed rows (compile-time folds)
        #define GETEL(i, j) (((j) & 1) ? WA[RS(i) + ((j) >> 1) - ((i) >> 1)].y \
                                       : WA[RS(i) + ((j) >> 1) - ((i) >> 1)].x)

        // ---- fp32 LDL^T (sqrt-free), packed row updates ----
        float idv[8];
        #pragma unroll
        for (int i = 0; i < 8; i++) {
            #pragma unroll
            for (int k = 0; k < i; k++) {
                const float c = GETEL(k, i) * idv[k];
                const v2f cb = (v2f){c, c};
                #pragma unroll
                for (int p = i >> 1; p < 4; p++)
                    WA[RS(i) + p - (i >> 1)] = __builtin_elementwise_fma(
                        -cb, WA[RS(k) + p - (k >> 1)], WA[RS(i) + p - (i >> 1)]);
            }
            idv[i] = frcp_fast(GETEL(i, i));
        }

        // forward: vt_i = idv_i * (cf_i - sum_{k<i} R_ki * vt_k)   (scalar)
        float vt[8];
        #pragma unroll
        for (int i = 0; i < 8; i++) {
            float s = cf[i];
            #pragma unroll
            for (int k = 0; k < i; k++)
                s = fmaf(-GETEL(k, i), vt[k], s);
            vt[i] = s * idv[i];
        }
        // back: w_i = vt_i - idv_i * sum_{j>i} R_ij * w_j          (scalar)
        float w[8];
        #pragma unroll
        for (int i = 7; i >= 0; i--) {
            float t = 0.f;
            #pragma unroll
            for (int j = i + 1; j < 8; j++)
                t = fmaf(GETEL(i, j), w[j], t);
            w[i] = fmaf(-idv[i], t, vt[i]);
        }
        #undef GETEL

        // ---- deferred AtY taps + packed output dots (ALL lanes) ----
        v2f wp[4];
        wp[0] = (v2f){w[0], w[1]}; wp[1] = (v2f){w[2], w[3]};
        wp[2] = (v2f){w[4], w[5]}; wp[3] = (v2f){w[6], w[7]};
        v2f CYt[12];
        htapv<6>(&CY[0], &CYt[0], idxm4);
        htapv<6>(&CY[6], &CYt[6], idxm4);
        float r[3];
        #pragma unroll
        for (int c = 0; c < 3; c++) {
            v2f a2 = (v2f){0.f, 0.f};
            #pragma unroll
            for (int p = 0; p < 4; p++)
                a2 = __builtin_elementwise_fma(wp[p], CYt[c * 4 + p], a2);
            r[c] = a2.x + a2.y;
        }

        if (do_store) {
            const int p = y * WW + px;
            #pragma unroll
            for (int c = 0; c < 3; c++)
                out[c * HW + p] = r[c];
        }
    }
}

extern "C" void kernel_launch(void* const* d_in, const int* in_sizes, int n_in,
                              void* d_out, int out_size, void* d_ws, size_t ws_size,
                              hipStream_t stream) {
    const float* inp = (const float*)d_in[0];
    const float* dep = (const float*)d_in[1];
    const float* alb = (const float*)d_in[2];
    const float* nrm = (const float*)d_in[3];
    float* out = (float*)d_out;
    dim3 grid((WW + OUTW - 1) / OUTW, HH / (RPB * WPB));   // 18 x 64, 256-thr blocks
    ls_sep_kernel<<<grid, dim3(WPB * 64), 0, stream>>>(inp, dep, alb, nrm, out);
}

// Round 17
// 126.015 us; speedup vs baseline: 1.2435x; 1.0873x over previous
//
#include <hip/hip_runtime.h>
#include <math.h>

#define HH 1024
#define WW 1024
#define OUTW 58            // output columns per wave (64 lanes - 6 halo)
#define RPB 4              // output rows per WAVE (vertical slide length)
#define WPB 4              // waves per block (independent y-strips, no barrier)
#define OFF(i) ((i)*8 - (i)*((i)-1)/2)   // packed upper-tri row offset

// ===== FINAL KERNEL (champion from rounds 9/12, 56.3 us) =====
// Hard-won constraints (rounds 4..16):
//  - VGPR bucket MUST stay 128: residency scales with the bucket cap
//    (occ% 34/16/9.7 at VGPR 64/128/216); regs-for-ILP sells waves and
//    VALUBusy DROPS (r11). Peak live floats <= ~120 or the allocator
//    spills at 128 rather than going to 256 (r7: 40 MB, r16: 39 MB).
//    WRITE_SIZE ~13.5 MB is the no-spill invariant.
//  - Cross-lane ops (DPP/bpermute) never inside divergent flow (r8).
//  - s_waitcnt vmcnt(0) drains ALL VMEM incl. output stores -> per-iter
//    LDS-ring prefetch serializes the loop (r15).
//  - TLP up (r13), TLP down (r10), packed fp32 (r16): all regressed.
//  - Structural accounting: ~900 VALU/row-iter = ~12 us pure-issue floor;
//    measured 56 us is a latency plateau at ~5 resident waves/CU
//    (invariant to grid shape / block size / VGPR bucket).

// DPP move, bound_ctrl=1 (invalid lanes read 0)
template<int CTRL>
__device__ __forceinline__ float dpp0(float x) {
    return __int_as_float(
        __builtin_amdgcn_update_dpp(0, __float_as_int(x), CTRL, 0xf, 0xf, true));
}
// whole-wave shift right by 1 lane (crosses 16-lane row boundaries)
__device__ __forceinline__ float wshr1(float x) { return dpp0<0x138>(x); }

// fp32 reciprocal: v_rcp_f32 + 1 Newton step (~1ulp); LDL^T is sqrt-free
__device__ __forceinline__ float frcp_fast(float s) {
    float r = __builtin_amdgcn_rcpf(s);
    return r * fmaf(-s, r, 2.0f);
}

__global__ __launch_bounds__(WPB * 64, 2) void ls_sep_kernel(
    const float* __restrict__ inp,    // [3,H,W]
    const float* __restrict__ dep,    // [1,H,W]
    const float* __restrict__ alb,    // [3,H,W]
    const float* __restrict__ nrm,    // [3,H,W]
    float* __restrict__ out)          // [3,H,W]
{
    const int L  = threadIdx.x & 63;          // lane 0..63
    const int wv = threadIdx.x >> 6;          // wave 0..3 (independent y-strip)
    const int HW = HH * WW;
    // lane L sums column x; its horizontal window (x-6..x) is centered at x-3
    const int x  = OUTW * blockIdx.x - 3 + L;
    const int y0 = (RPB * WPB) * blockIdx.y + RPB * wv;
    const int px = x - 3;                     // output pixel column for this lane

    const int xc    = min(max(x, 0), WW - 1);
    const float xok = (x >= 0 && x < WW) ? 1.f : 0.f;

    float C[60];                              // running column sums (7 rows in y)
    #pragma unroll
    for (int k = 0; k < 60; k++) C[k] = 0.f;

    auto acc_row = [&](int yy, float sgn) {
        const int yc = min(max(yy, 0), HH - 1);
        const float ok = (yy >= 0 && yy < HH) ? xok : 0.f;
        const int p = yc * WW + xc;
        float fv[8], yv[3];
        fv[0] = 1.f;
        fv[1] = dep[p];
        fv[2] = alb[p];
        fv[3] = alb[p + HW];
        fv[4] = alb[p + 2 * HW];
        fv[5] = nrm[p];
        fv[6] = nrm[p + HW];
        fv[7] = nrm[p + 2 * HW];
        yv[0] = inp[p];
        yv[1] = inp[p + HW];
        yv[2] = inp[p + 2 * HW];
        const float s = sgn * ok;
        float fs[8];
        #pragma unroll
        for (int i = 0; i < 8; i++) fs[i] = fv[i] * s;
        int k = 0;
        #pragma unroll
        for (int i = 0; i < 8; i++)
            #pragma unroll
            for (int j = i; j < 8; j++) { C[k] = fmaf(fs[i], fv[j], C[k]); k++; }
        #pragma unroll
        for (int i = 0; i < 8; i++)
            #pragma unroll
            for (int c = 0; c < 3; c++)
                C[36 + i * 3 + c] = fmaf(fs[i], yv[c], C[36 + i * 3 + c]);
    };

    // preload rows y0-4 .. y0+2 (loop body does add(y+3), sub(y-4))
    #pragma unroll 1
    for (int yy = y0 - 4; yy < y0 + 3; yy++) acc_row(yy, 1.f);

    const int idxm4 = ((L - 4) & 63) << 2;    // bpermute byte index for lane L-4
    const int pxc = min(max(px, 0), WW - 1);
    const bool do_store = (L >= 6) && (px < WW);

    // Batched horizontal 7-tap over lanes L-6..L for 12 values at once.
    // MUST be called by all 64 lanes (cross-lane inside).
    auto htap12 = [&](int base, float* dst) {
        float t2a[12];
        int pma[12];
        #pragma unroll
        for (int j = 0; j < 12; j++) {
            const float xv = C[base + j];
            const float w1 = wshr1(xv);       // C(L-1)
            const float t1 = xv + w1;         // L-1..L
            const float w2 = wshr1(w1);       // C(L-2)
            const float t3 = t1 + w2;         // L-2..L
            const float w3 = wshr1(w2);       // C(L-3)
            t2a[j] = t3 + w3;                 // L-3..L
            pma[j] = __builtin_amdgcn_ds_bpermute(idxm4, __float_as_int(t3));
        }
        #pragma unroll
        for (int j = 0; j < 12; j++)
            dst[j] = t2a[j] + __int_as_float(pma[j]);   // + (L-6..L-4)
    };

    #pragma unroll 1
    for (int y = y0; y < y0 + RPB; y++) {
        acc_row(y + 3, 1.f);
        acc_row(y - 4, -1.f);

        // center-pixel features EARLY: global-load latency hides under taps
        const int pc = y * WW + pxc;
        float cf[8];
        cf[0] = 1.f;
        cf[1] = dep[pc];
        cf[2] = alb[pc]; cf[3] = alb[pc + HW]; cf[4] = alb[pc + 2 * HW];
        cf[5] = nrm[pc]; cf[6] = nrm[pc + HW]; cf[7] = nrm[pc + 2 * HW];

        // ---- horizontal taps for AtA (AtY deferred past the solve) ----
        float W[36];
        htap12(0,  &W[0]);
        htap12(12, &W[12]);
        htap12(24, &W[24]);
        #pragma unroll
        for (int i = 0; i < 8; i++) W[OFF(i)] += 1.0e-4f;

        // ---- fp32 LDL^T (sqrt-free). W row i keeps R_ij = d_i*U_ij ----
        float idv[8];
        #pragma unroll
        for (int i = 0; i < 8; i++) {
            #pragma unroll
            for (int k = 0; k < i; k++) {
                const float c = W[OFF(k) + i - k] * idv[k];   // U_ki
                #pragma unroll
                for (int j = i; j < 8; j++)
                    W[OFF(i) + j - i] = fmaf(-c, W[OFF(k) + j - k], W[OFF(i) + j - i]);
            }
            idv[i] = frcp_fast(W[OFF(i)]);    // 1/d_i
        }

        // forward: vt_i = idv_i * (cf_i - sum_{k<i} R_ki * vt_k)
        float vt[8];
        #pragma unroll
        for (int i = 0; i < 8; i++) {
            float s = cf[i];
            #pragma unroll
            for (int k = 0; k < i; k++)
                s = fmaf(-W[OFF(k) + i - k], vt[k], s);
            vt[i] = s * idv[i];
        }
        // back: w_i = vt_i - idv_i * sum_{j>i} R_ij * w_j
        float w[8];
        #pragma unroll
        for (int i = 7; i >= 0; i--) {
            float t = 0.f;
            #pragma unroll
            for (int j = i + 1; j < 8; j++)
                t = fmaf(W[OFF(i) + j - i], w[j], t);
            w[i] = fmaf(-idv[i], t, vt[i]);
        }

        // ---- deferred AtY taps (batched) + output dot products:
        //      ALL lanes execute; only the store is predicated ----
        float r[3] = {0.f, 0.f, 0.f};
        {
            float SY[12];
            htap12(36, SY);                   // AtY for i=0..3
            #pragma unroll
            for (int i = 0; i < 4; i++)
                #pragma unroll
                for (int c = 0; c < 3; c++)
                    r[c] = fmaf(w[i], SY[i * 3 + c], r[c]);
            htap12(48, SY);                   // AtY for i=4..7
            #pragma unroll
            for (int i = 0; i < 4; i++)
                #pragma unroll
                for (int c = 0; c < 3; c++)
                    r[c] = fmaf(w[i + 4], SY[i * 3 + c], r[c]);
        }

        if (do_store) {
            const int p = y * WW + px;
            #pragma unroll
            for (int c = 0; c < 3; c++)
                out[c * HW + p] = r[c];
        }
    }
}

extern "C" void kernel_launch(void* const* d_in, const int* in_sizes, int n_in,
                              void* d_out, int out_size, void* d_ws, size_t ws_size,
                              hipStream_t stream) {
    const float* inp = (const float*)d_in[0];
    const float* dep = (const float*)d_in[1];
    const float* alb = (const float*)d_in[2];
    const float* nrm = (const float*)d_in[3];
    float* out = (float*)d_out;
    dim3 grid((WW + OUTW - 1) / OUTW, HH / (RPB * WPB));   // 18 x 64, 256-thr blocks
    ls_sep_kernel<<<grid, dim3(WPB * 64), 0, stream>>>(inp, dep, alb, nrm, out);
}